// Round 4
// baseline (174.042 us; speedup 1.0000x reference)
//
#include <hip/hip_runtime.h>
#include <hip/hip_bf16.h>
#include <hip/hip_cooperative_groups.h>

namespace cg = cooperative_groups;

// LearnableChebyshevKernelAttention, MI355X — single cooperative kernel:
// prep -> grid.sync -> cheb_attn -> grid.sync -> proj. Phase numerics are
// BYTE-IDENTICAL to the verified round-3 three-kernel version (absmax 1.95e-3).
// B=2, Q=M=1024, DIM=3, H=8, V=64, OUT=512, C=8.
//
// prep:  values [b,m,h,v] f32 -> Vt [b,h,v,m] bf16, out_w f32 -> bf16.
// cheb:  bid -> (qt,h,b); 8 waves; scores computed directly in the MFMA
//        A-fragment register layout; no score LDS, no per-tile barriers.
// proj:  flat bf16 [2048,512] @ Wb[n,k]^T via MFMA, frags from L2-resident
//        global; 8 waves each own one 16x16 output tile chain (same MFMA
//        order as before -> bit-identical).
// Fallback: if hipLaunchCooperativeKernel fails, run the same three phases
// as separate kernels (same bodies, same numerics).

typedef __attribute__((ext_vector_type(8))) short short8v;
typedef __attribute__((ext_vector_type(4))) short short4v;
typedef __attribute__((ext_vector_type(4))) float f32x4;

#define EPSF 1e-5f

__device__ __forceinline__ float frcp(float x) { return __builtin_amdgcn_rcpf(x); }
__device__ __forceinline__ short f2bf(float f) {
    __hip_bfloat16 h = __float2bfloat16(f);   // RNE
    return *reinterpret_cast<short*>(&h);
}

// ws layout (shorts): Vt bf16 [2*8*64*1024] | Wb bf16 [512*512] | flat bf16 [2*1024*512]
#define VT_ELEMS   (2u * 8u * 64u * 1024u)
#define WB_OFF_S   (VT_ELEMS)
#define FLAT_OFF_S (VT_ELEMS + 512u * 512u)

// ---------------------------------------------------------------- prep body
// 512 threads. bid 0..255: transpose one (b,h,64m) values tile; 256..287: W.
__device__ __forceinline__ void prep_body(int bid, int t,
    const float* __restrict__ vals, const float* __restrict__ outw,
    short* __restrict__ vt, short* __restrict__ wb)
{
    if (bid < 256) {
        __shared__ float sf[64 * 68];
        const int b = bid >> 7, h = (bid >> 4) & 7, m0 = (bid & 15) * 64;
        #pragma unroll
        for (int fi = 0; fi < 2; ++fi) {
            const int idx = fi * 512 + t, mr = idx >> 4, c4 = idx & 15;
            const float4 v4 = *(const float4*)&vals[
                (((size_t)b * 1024 + m0 + mr) * 8 + h) * 64 + c4 * 4];
            *(float4*)&sf[mr * 68 + c4 * 4] = v4;
        }
        __syncthreads();
        const int v = t >> 3, mo = t & 7;            // 64 v x 8 m-octets
        short8v o0;
        #pragma unroll
        for (int i = 0; i < 8; ++i) o0[i] = f2bf(sf[(mo * 8 + i) * 68 + v]);
        const size_t ob = ((size_t)(b * 8 + h) * 64 + v) * 1024 + m0 + mo * 8;
        *(short8v*)&vt[ob] = o0;
    } else if (bid < 288) {
        const int wi = bid - 256;                    // 0..31, 8192 floats each
        #pragma unroll
        for (int k = 0; k < 4; ++k) {
            const int fidx = wi * 8192 + k * 2048 + t * 4;
            const float4 f4 = *(const float4*)&outw[fidx];
            short4v s; s[0] = f2bf(f4.x); s[1] = f2bf(f4.y);
                       s[2] = f2bf(f4.z); s[3] = f2bf(f4.w);
            *(short4v*)&wb[fidx] = s;
        }
    }
}

// ---------------------------------------------------------------- cheb body
// 512 threads (8 waves). bid -> qt=bid&31, h=(bid>>5)&7, b=bid>>8.
__device__ __forceinline__ void cheb_body(int bid, int t,
    const float* __restrict__ qp, const float* __restrict__ kp,
    const unsigned char* __restrict__ msk,
    const float* __restrict__ ls, const float* __restrict__ cheb,
    const short* __restrict__ vt, short* __restrict__ flatb)
{
    __shared__ float s_kx[1024], s_ky[1024], s_kz[1024];   // kp SoA
    __shared__ __align__(8) unsigned char s_mask[1024];
    __shared__ float s_l1[4][32];
    __shared__ float s_pb[3][32 * 68];                      // groups 1..3 partial P

    const int qt = bid & 31, h = (bid >> 5) & 7, b = bid >> 8;
    const int w = t >> 6, lane = t & 63;
    const int wg = w & 1, g = w >> 1;          // q band (16 rows), m group (256 m)
    const int arow = lane & 15, koct = lane >> 4;

    // stage kp (SoA) + mask
    #pragma unroll
    for (int mm_ = 0; mm_ < 2; ++mm_) {
        const int m = mm_ * 512 + t;
        const size_t base = ((size_t)b * 1024 + m) * 3;
        s_kx[m] = kp[base + 0];
        s_ky[m] = kp[base + 1];
        s_kz[m] = kp[base + 2];
    }
    *(unsigned short*)&s_mask[t * 2] =
        *(const unsigned short*)&msk[(size_t)b * 1024 + t * 2];

    // per-head constants (wave-uniform -> scalar regs). Verified numerics.
    const float lsv = ls[h];
    const float invls2 = 1.0f / (lsv * lsv);
    float cc[8]; float cs = 0.f;
    #pragma unroll
    for (int j = 0; j < 8; ++j) { cc[j] = cheb[h * 8 + j]; cs += cc[j]; }
    const float cm = cs * 0.125f;
    #pragma unroll
    for (int j = 0; j < 8; ++j) cc[j] -= cm;

    // this lane's q row (A-fragment row identity)
    const int qg = qt * 32 + wg * 16 + arow;
    const float qx = qp[((size_t)b * 1024 + qg) * 3 + 0];
    const float qy = qp[((size_t)b * 1024 + qg) * 3 + 1];
    const float qz = qp[((size_t)b * 1024 + qg) * 3 + 2];

    f32x4 acc[4] = {(f32x4)(0.f), (f32x4)(0.f), (f32x4)(0.f), (f32x4)(0.f)};
    const short* vtb = vt + ((size_t)(b * 8 + h) * 64) * 1024;
    float l1p = 0.f;

    __syncthreads();   // kp/mask staged — the ONLY pre-epilogue block barrier

    #pragma unroll
    for (int tile = 0; tile < 4; ++tile) {
        const int m0 = g * 256 + tile * 64;

        // ---- 1) issue Vt B-frag loads (L2/IC) — consumed only at step 3
        short8v bfr[2][4];
        #pragma unroll
        for (int kk = 0; kk < 2; ++kk)
            #pragma unroll
            for (int f = 0; f < 4; ++f)
                bfr[kk][f] = *(const short8v*)
                    &vtb[(size_t)(f * 16 + arow) * 1024 + m0 + kk * 32 + koct * 8];

        // ---- 1b) LDS k reads + mask for both kk groups
        f32x4 kx[2][2], ky[2][2], kz[2][2];
        uint2 mmv[2];
        #pragma unroll
        for (int kk = 0; kk < 2; ++kk) {
            const int mb = m0 + kk * 32 + koct * 8;
            kx[kk][0] = *(const f32x4*)&s_kx[mb]; kx[kk][1] = *(const f32x4*)&s_kx[mb + 4];
            ky[kk][0] = *(const f32x4*)&s_ky[mb]; ky[kk][1] = *(const f32x4*)&s_ky[mb + 4];
            kz[kk][0] = *(const f32x4*)&s_kz[mb]; kz[kk][1] = *(const f32x4*)&s_kz[mb + 4];
            mmv[kk] = *(const uint2*)&s_mask[mb];
        }

        // ---- 2) 16 scores, verified Chebyshev-recurrence numerics
        short8v a[2];
        #pragma unroll
        for (int kk = 0; kk < 2; ++kk) {
            const bool anymask = (mmv[kk].x | mmv[kk].y) != 0u;
            #pragma unroll
            for (int j = 0; j < 8; ++j) {
                const float dx = qx - kx[kk][j >> 2][j & 3];
                const float dy = qy - ky[kk][j >> 2][j & 3];
                const float dz = qz - kz[kk][j >> 2][j & 3];
                const float x  = (dx * dx + dy * dy + dz * dz) * invls2;
                const float r  = (x - 1.f) * frcp(x + 1.f);
                const float r2 = r + r;
                float tp = 1.f, tc = r;
                float s  = cc[0] + cc[1] * r;
                #pragma unroll
                for (int c = 2; c < 8; ++c) {
                    const float tn = r2 * tc - tp;
                    s += cc[c] * tn; tp = tc; tc = tn;
                }
                if (anymask) {
                    const unsigned int mword = (j < 4) ? mmv[kk].x : mmv[kk].y;
                    if ((mword >> ((j & 3) * 8)) & 0xffu) s = 0.f;
                }
                l1p += fabsf(s);
                a[kk][j] = f2bf(s);
            }
        }

        // ---- 3) attend
        #pragma unroll
        for (int kk = 0; kk < 2; ++kk)
            #pragma unroll
            for (int f = 0; f < 4; ++f)
                acc[f] = __builtin_amdgcn_mfma_f32_16x16x32_bf16(
                    a[kk], bfr[kk][f], acc[f], 0, 0, 0);
    }

    // L1 partial: lanes {arow, arow+16, arow+32, arow+48} share q row
    l1p += __shfl_xor(l1p, 16);
    l1p += __shfl_xor(l1p, 32);
    if (koct == 0) s_l1[g][wg * 16 + arow] = l1p;

    if (g > 0) {
        #pragma unroll
        for (int f = 0; f < 4; ++f)
            #pragma unroll
            for (int j = 0; j < 4; ++j)
                s_pb[g - 1][(wg * 16 + koct * 4 + j) * 68 + f * 16 + arow] = acc[f][j];
    }
    __syncthreads();
    if (g == 0) {
        float rden[4];
        #pragma unroll
        for (int j = 0; j < 4; ++j) {
            const int row = wg * 16 + koct * 4 + j;
            rden[j] = frcp(s_l1[0][row] + s_l1[1][row] + s_l1[2][row]
                         + s_l1[3][row] + EPSF);
        }
        #pragma unroll
        for (int f = 0; f < 4; ++f)
            #pragma unroll
            for (int j = 0; j < 4; ++j) {
                const int row = wg * 16 + koct * 4 + j;
                const int col = f * 16 + arow;
                const float v = (acc[f][j]
                    + s_pb[0][row * 68 + col]
                    + s_pb[1][row * 68 + col]
                    + s_pb[2][row * 68 + col]) * rden[j];
                flatb[((size_t)b * 1024 + qt * 32 + row) * 512 + h * 64 + col]
                    = f2bf(v);
            }
    }
}

// ---------------------------------------------------------------- proj body
// 512 threads (8 waves). bid -> r0=(bid&31)*64, n0=(bid>>5)*32.
// Wave w: rows band=(w&3)*16, n half fh=w>>2. Single acc chain over k=512
// in the same kk order as before -> bit-identical accumulation.
__device__ __forceinline__ void proj_body(int bid, int t,
    const short* __restrict__ flatb, const short* __restrict__ wb,
    float* __restrict__ out)
{
    const int r0 = (bid & 31) * 64, n0 = (bid >> 5) * 32;
    const int w = t >> 6, lane = t & 63;
    const int arow = lane & 15, koct = lane >> 4;
    const int band = (w & 3) * 16, fh = w >> 2;

    f32x4 acc = (f32x4)(0.f);
    const short* ap = &flatb[(size_t)(r0 + band + arow) * 512];
    const short* bp = &wb[(size_t)(n0 + fh * 16 + arow) * 512];

    #pragma unroll 8
    for (int kk = 0; kk < 16; ++kk) {
        const int ko = kk * 32 + koct * 8;
        const short8v a  = *(const short8v*)&ap[ko];
        const short8v bf = *(const short8v*)&bp[ko];
        acc = __builtin_amdgcn_mfma_f32_16x16x32_bf16(a, bf, acc, 0, 0, 0);
    }
    #pragma unroll
    for (int j = 0; j < 4; ++j)
        out[((size_t)(r0 + band + koct * 4 + j)) * 512 + n0 + fh * 16 + arow]
            = acc[j];
}

// ---------------------------------------------------------------- kernels
__global__ __launch_bounds__(512, 4) void fused(
    const float* __restrict__ qp, const float* __restrict__ kp,
    const float* __restrict__ vals, const unsigned char* __restrict__ msk,
    const float* __restrict__ ls, const float* __restrict__ cheb,
    const float* __restrict__ outw,
    short* __restrict__ vt, short* __restrict__ wb,
    short* __restrict__ flatb, float* __restrict__ out)
{
    const int bid = blockIdx.x, t = threadIdx.x;
    prep_body(bid, t, vals, outw, vt, wb);
    cg::this_grid().sync();
    cheb_body(bid, t, qp, kp, msk, ls, cheb, vt, flatb);
    cg::this_grid().sync();
    proj_body(bid, t, flatb, wb, out);
}

__global__ __launch_bounds__(512) void prep_k(
    const float* __restrict__ vals, const float* __restrict__ outw,
    short* __restrict__ vt, short* __restrict__ wb)
{
    prep_body(blockIdx.x, threadIdx.x, vals, outw, vt, wb);
}

__global__ __launch_bounds__(512, 4) void cheb_k(
    const float* __restrict__ qp, const float* __restrict__ kp,
    const unsigned char* __restrict__ msk,
    const float* __restrict__ ls, const float* __restrict__ cheb,
    const short* __restrict__ vt, short* __restrict__ flatb)
{
    cheb_body(blockIdx.x, threadIdx.x, qp, kp, msk, ls, cheb, vt, flatb);
}

__global__ __launch_bounds__(512, 4) void proj_k(
    const short* __restrict__ flatb, const short* __restrict__ wb,
    float* __restrict__ out)
{
    proj_body(blockIdx.x, threadIdx.x, flatb, wb, out);
}

extern "C" void kernel_launch(void* const* d_in, const int* in_sizes, int n_in,
                              void* d_out, int out_size, void* d_ws, size_t ws_size,
                              hipStream_t stream) {
    const float* qp   = (const float*)d_in[0];
    const float* kp   = (const float*)d_in[1];
    const float* vals = (const float*)d_in[2];
    const unsigned char* msk = (const unsigned char*)d_in[3];
    const float* ls   = (const float*)d_in[4];
    const float* cheb = (const float*)d_in[5];
    const float* outw = (const float*)d_in[6];
    float* out = (float*)d_out;

    short* vtp   = (short*)d_ws;
    short* wbp   = vtp + WB_OFF_S;
    short* flatb = vtp + FLAT_OFF_S;

    void* args[] = {(void*)&qp, (void*)&kp, (void*)&vals, (void*)&msk,
                    (void*)&ls, (void*)&cheb, (void*)&outw,
                    (void*)&vtp, (void*)&wbp, (void*)&flatb, (void*)&out};
    hipError_t e = hipLaunchCooperativeKernel((const void*)fused,
                                              dim3(512), dim3(512),
                                              args, 0u, stream);
    if (e != hipSuccess) {
        // fallback: same bodies as three dispatches (same numerics)
        prep_k<<<288, 512, 0, stream>>>(vals, outw, vtp, wbp);
        cheb_k<<<512, 512, 0, stream>>>(qp, kp, msk, ls, cheb, vtp, flatb);
        proj_k<<<512, 512, 0, stream>>>(flatb, wbp, out);
    }
}

// Round 5
// 73.747 us; speedup vs baseline: 2.3600x; 2.3600x over previous
//
#include <hip/hip_runtime.h>
#include <hip/hip_bf16.h>

// LearnableChebyshevKernelAttention, MI355X — MFMA, barrier-free main loop,
// packed-FP32 (v_pk_*) score math. Three-kernel chain (cooperative fusion
// measured 4x WORSE: grid.sync costs ~55us/sync on 8-XCD L2 coherence).
// Per-component score numerics BIT-IDENTICAL to the verified round-3 kernel.
// B=2, Q=M=1024, DIM=3, H=8, V=64, OUT=512, C=8.
//
// prep:      values [b,m,h,v] f32 -> Vt [b,h,v,m] bf16, out_w f32 -> bf16.
// cheb_attn: grid (32,8,2) = (qt of 32 q, h, b), block 512 (8 waves).
//            Scores computed directly in the MFMA A-fragment register layout
//            (lane arow owns q; koct owns an 8-m octet) as 4 float2 pairs ->
//            compiler emits dual-pumped v_pk_fma_f32 etc. No score LDS, no
//            per-tile barriers.
// proj:      flat bf16 [2048,512] @ Wb[n,k]^T via MFMA, frags straight from
//            L2-resident global, no LDS, no barriers. grid (32,16), block 256.

typedef __attribute__((ext_vector_type(8))) short short8v;
typedef __attribute__((ext_vector_type(4))) short short4v;
typedef __attribute__((ext_vector_type(4))) float f32x4;
typedef __attribute__((ext_vector_type(2))) float f32x2;

#define EPSF 1e-5f

__device__ __forceinline__ float frcp(float x) { return __builtin_amdgcn_rcpf(x); }
__device__ __forceinline__ short f2bf(float f) {
    __hip_bfloat16 h = __float2bfloat16(f);   // RNE
    return *reinterpret_cast<short*>(&h);
}

// ws layout (shorts): Vt bf16 [2*8*64*1024] | Wb bf16 [512*512] | flat bf16 [2*1024*512]
#define VT_ELEMS   (2u * 8u * 64u * 1024u)
#define WB_OFF_S   (VT_ELEMS)
#define FLAT_OFF_S (VT_ELEMS + 512u * 512u)

// ---------------------------------------------------------------- prep
// grid 288: blocks 0..255 transpose one (b,h,64m) values tile; 256..287 convert W.
__global__ __launch_bounds__(256) void prep(
    const float* __restrict__ vals, const float* __restrict__ outw,
    short* __restrict__ vt, short* __restrict__ wb)
{
    const int bid = blockIdx.x, t = threadIdx.x;
    if (bid < 256) {
        __shared__ float sf[64 * 68];
        const int b = bid >> 7, h = (bid >> 4) & 7, m0 = (bid & 15) * 64;
        #pragma unroll
        for (int fi = 0; fi < 4; ++fi) {
            const int idx = fi * 256 + t, mr = idx >> 4, c4 = idx & 15;
            const float4 v4 = *(const float4*)&vals[
                (((size_t)b * 1024 + m0 + mr) * 8 + h) * 64 + c4 * 4];
            *(float4*)&sf[mr * 68 + c4 * 4] = v4;
        }
        __syncthreads();
        const int v = t >> 2, mo = t & 3;
        short8v o0, o1;
        #pragma unroll
        for (int i = 0; i < 8; ++i) o0[i] = f2bf(sf[(mo * 16 + i) * 68 + v]);
        #pragma unroll
        for (int i = 0; i < 8; ++i) o1[i] = f2bf(sf[(mo * 16 + 8 + i) * 68 + v]);
        const size_t ob = ((size_t)(b * 8 + h) * 64 + v) * 1024 + m0 + mo * 16;
        *(short8v*)&vt[ob] = o0;
        *(short8v*)&vt[ob + 8] = o1;
    } else {
        const int wi = bid - 256;            // 0..31, 8192 floats each
        #pragma unroll
        for (int k = 0; k < 8; ++k) {
            const int fidx = wi * 8192 + k * 1024 + t * 4;
            const float4 f4 = *(const float4*)&outw[fidx];
            short4v s; s[0] = f2bf(f4.x); s[1] = f2bf(f4.y);
                       s[2] = f2bf(f4.z); s[3] = f2bf(f4.w);
            *(short4v*)&wb[fidx] = s;
        }
    }
}

// ---------------------------------------------------------------- cheb_attn
// grid (32, 8, 2) = (qt, h, b), block 512 (8 waves), 2 blocks/CU.
__global__ __launch_bounds__(512, 4) void cheb_attn(
    const float* __restrict__ qp, const float* __restrict__ kp,
    const unsigned char* __restrict__ msk,
    const float* __restrict__ ls, const float* __restrict__ cheb,
    const short* __restrict__ vt, short* __restrict__ flatb)
{
    __shared__ float s_kx[1024], s_ky[1024], s_kz[1024];   // kp SoA
    __shared__ __align__(8) unsigned char s_mask[1024];
    __shared__ float s_l1[4][32];
    __shared__ float s_pb[3][32 * 68];                      // groups 1..3 partial P

    const int t = threadIdx.x;
    const int qt = blockIdx.x, h = blockIdx.y, b = blockIdx.z;
    const int w = t >> 6, lane = t & 63;
    const int wg = w & 1, g = w >> 1;          // q band (16 rows), m group (256 m)
    const int arow = lane & 15, koct = lane >> 4;

    // stage kp (SoA) + mask
    #pragma unroll
    for (int mm_ = 0; mm_ < 2; ++mm_) {
        const int m = mm_ * 512 + t;
        const size_t base = ((size_t)b * 1024 + m) * 3;
        s_kx[m] = kp[base + 0];
        s_ky[m] = kp[base + 1];
        s_kz[m] = kp[base + 2];
    }
    *(unsigned short*)&s_mask[t * 2] =
        *(const unsigned short*)&msk[(size_t)b * 1024 + t * 2];

    // per-head constants (wave-uniform -> scalar regs). Verified numerics.
    const float lsv = ls[h];
    const float invls2 = 1.0f / (lsv * lsv);
    float cc[8]; float cs = 0.f;
    #pragma unroll
    for (int j = 0; j < 8; ++j) { cc[j] = cheb[h * 8 + j]; cs += cc[j]; }
    const float cm = cs * 0.125f;
    #pragma unroll
    for (int j = 0; j < 8; ++j) cc[j] -= cm;

    // this lane's q row (A-fragment row identity)
    const int qg = qt * 32 + wg * 16 + arow;
    const float qx = qp[((size_t)b * 1024 + qg) * 3 + 0];
    const float qy = qp[((size_t)b * 1024 + qg) * 3 + 1];
    const float qz = qp[((size_t)b * 1024 + qg) * 3 + 2];

    f32x4 acc[4] = {(f32x4)(0.f), (f32x4)(0.f), (f32x4)(0.f), (f32x4)(0.f)};
    const short* vtb = vt + ((size_t)(b * 8 + h) * 64) * 1024;
    f32x2 l1v = (f32x2)(0.f);     // even/odd partial L1 sums (folded once at end)

    __syncthreads();   // kp/mask staged — the ONLY pre-epilogue barrier

    #pragma unroll
    for (int tile = 0; tile < 4; ++tile) {
        const int m0 = g * 256 + tile * 64;

        // ---- 1) issue Vt B-frag loads (L2) — consumed only at step 3
        short8v bfr[2][4];
        #pragma unroll
        for (int kk = 0; kk < 2; ++kk)
            #pragma unroll
            for (int f = 0; f < 4; ++f)
                bfr[kk][f] = *(const short8v*)
                    &vtb[(size_t)(f * 16 + arow) * 1024 + m0 + kk * 32 + koct * 8];

        // ---- 1b) LDS k reads (b128) + mask for both kk groups
        f32x4 kx[2][2], ky[2][2], kz[2][2];
        uint2 mmv[2];
        #pragma unroll
        for (int kk = 0; kk < 2; ++kk) {
            const int mb = m0 + kk * 32 + koct * 8;
            kx[kk][0] = *(const f32x4*)&s_kx[mb]; kx[kk][1] = *(const f32x4*)&s_kx[mb + 4];
            ky[kk][0] = *(const f32x4*)&s_ky[mb]; ky[kk][1] = *(const f32x4*)&s_ky[mb + 4];
            kz[kk][0] = *(const f32x4*)&s_kz[mb]; kz[kk][1] = *(const f32x4*)&s_kz[mb + 4];
            mmv[kk] = *(const uint2*)&s_mask[mb];
        }

        // ---- 2) 16 scores as 8 float2 pairs (v_pk_* dual-pumped f32).
        //         Per-component op sequence identical to round-3 scalar code.
        short8v a[2];
        #pragma unroll
        for (int kk = 0; kk < 2; ++kk) {
            const bool anymask = (mmv[kk].x | mmv[kk].y) != 0u;
            #pragma unroll
            for (int p = 0; p < 4; ++p) {          // pair = scores j=2p, 2p+1
                f32x2 kxp, kyp, kzp;
                kxp[0] = kx[kk][p >> 1][(p & 1) * 2 + 0];
                kxp[1] = kx[kk][p >> 1][(p & 1) * 2 + 1];
                kyp[0] = ky[kk][p >> 1][(p & 1) * 2 + 0];
                kyp[1] = ky[kk][p >> 1][(p & 1) * 2 + 1];
                kzp[0] = kz[kk][p >> 1][(p & 1) * 2 + 0];
                kzp[1] = kz[kk][p >> 1][(p & 1) * 2 + 1];
                const f32x2 dx = qx - kxp;
                const f32x2 dy = qy - kyp;
                const f32x2 dz = qz - kzp;
                const f32x2 x  = (dx * dx + dy * dy + dz * dz) * invls2;
                f32x2 rc; rc[0] = frcp(x[0] + 1.f); rc[1] = frcp(x[1] + 1.f);
                const f32x2 r  = (x - 1.f) * rc;
                const f32x2 r2 = r + r;
                f32x2 tp = (f32x2)(1.f), tc = r;
                f32x2 s  = cc[0] + cc[1] * r;
                #pragma unroll
                for (int c = 2; c < 8; ++c) {
                    const f32x2 tn = r2 * tc - tp;
                    s += cc[c] * tn; tp = tc; tc = tn;
                }
                if (anymask) {
                    const unsigned int mword = (p < 2) ? mmv[kk].x : mmv[kk].y;
                    if ((mword >> (((p * 2)     & 3) * 8)) & 0xffu) s[0] = 0.f;
                    if ((mword >> (((p * 2 + 1) & 3) * 8)) & 0xffu) s[1] = 0.f;
                }
                l1v += __builtin_elementwise_abs(s);
                a[kk][p * 2]     = f2bf(s[0]);
                a[kk][p * 2 + 1] = f2bf(s[1]);
            }
        }

        // ---- 3) attend
        #pragma unroll
        for (int kk = 0; kk < 2; ++kk)
            #pragma unroll
            for (int f = 0; f < 4; ++f)
                acc[f] = __builtin_amdgcn_mfma_f32_16x16x32_bf16(
                    a[kk], bfr[kk][f], acc[f], 0, 0, 0);
    }

    // L1 partial: lanes {arow, arow+16, arow+32, arow+48} share q row
    float l1p = l1v[0] + l1v[1];
    l1p += __shfl_xor(l1p, 16);
    l1p += __shfl_xor(l1p, 32);
    if (koct == 0) s_l1[g][wg * 16 + arow] = l1p;

    if (g > 0) {
        #pragma unroll
        for (int f = 0; f < 4; ++f)
            #pragma unroll
            for (int j = 0; j < 4; ++j)
                s_pb[g - 1][(wg * 16 + koct * 4 + j) * 68 + f * 16 + arow] = acc[f][j];
    }
    __syncthreads();
    if (g == 0) {
        float rden[4];
        #pragma unroll
        for (int j = 0; j < 4; ++j) {
            const int row = wg * 16 + koct * 4 + j;
            rden[j] = frcp(s_l1[0][row] + s_l1[1][row] + s_l1[2][row]
                         + s_l1[3][row] + EPSF);
        }
        #pragma unroll
        for (int f = 0; f < 4; ++f)
            #pragma unroll
            for (int j = 0; j < 4; ++j) {
                const int row = wg * 16 + koct * 4 + j;
                const int col = f * 16 + arow;
                const float v = (acc[f][j]
                    + s_pb[0][row * 68 + col]
                    + s_pb[1][row * 68 + col]
                    + s_pb[2][row * 68 + col]) * rden[j];
                flatb[((size_t)b * 1024 + qt * 32 + row) * 512 + h * 64 + col]
                    = f2bf(v);
            }
    }
}

// ---------------------------------------------------------------- proj
// out[2048,512] = flat[2048,512] @ Wb[n,k]^T, bf16 MFMA, frags direct from
// L2-resident global. grid (32,16): 64 rows x 32 n per block; block 256.
__global__ __launch_bounds__(256, 4) void proj(
    const short* __restrict__ flatb, const short* __restrict__ wb,
    float* __restrict__ out)
{
    const int t = threadIdx.x;
    const int r0 = blockIdx.x * 64, n0 = blockIdx.y * 32;
    const int w = t >> 6, lane = t & 63;
    const int arow = lane & 15, koct = lane >> 4;
    const int band = w * 16;

    f32x4 acc[2] = {(f32x4)(0.f), (f32x4)(0.f)};
    const short* ap = &flatb[(size_t)(r0 + band + arow) * 512];
    const short* b0 = &wb[(size_t)(n0 + arow) * 512];
    const short* b1 = &wb[(size_t)(n0 + 16 + arow) * 512];

    #pragma unroll 8
    for (int kk = 0; kk < 16; ++kk) {
        const int ko = kk * 32 + koct * 8;
        const short8v a   = *(const short8v*)&ap[ko];
        const short8v bf0 = *(const short8v*)&b0[ko];
        const short8v bf1 = *(const short8v*)&b1[ko];
        acc[0] = __builtin_amdgcn_mfma_f32_16x16x32_bf16(a, bf0, acc[0], 0, 0, 0);
        acc[1] = __builtin_amdgcn_mfma_f32_16x16x32_bf16(a, bf1, acc[1], 0, 0, 0);
    }
    #pragma unroll
    for (int f = 0; f < 2; ++f)
        #pragma unroll
        for (int j = 0; j < 4; ++j)
            out[((size_t)(r0 + band + koct * 4 + j)) * 512 + n0 + f * 16 + arow]
                = acc[f][j];
}

extern "C" void kernel_launch(void* const* d_in, const int* in_sizes, int n_in,
                              void* d_out, int out_size, void* d_ws, size_t ws_size,
                              hipStream_t stream) {
    const float* qp   = (const float*)d_in[0];
    const float* kp   = (const float*)d_in[1];
    const float* vals = (const float*)d_in[2];
    const unsigned char* msk = (const unsigned char*)d_in[3];
    const float* ls   = (const float*)d_in[4];
    const float* cheb = (const float*)d_in[5];
    const float* outw = (const float*)d_in[6];
    float* out = (float*)d_out;

    short* vtp   = (short*)d_ws;
    short* wbp   = vtp + WB_OFF_S;
    short* flatb = vtp + FLAT_OFF_S;

    prep<<<288, 256, 0, stream>>>(vals, outw, vtp, wbp);
    cheb_attn<<<dim3(32, 8, 2), 512, 0, stream>>>(qp, kp, msk, ls, cheb, vtp, flatb);
    proj<<<dim3(32, 16), 256, 0, stream>>>(flatb, wbp, out);
}

// Round 6
// 43.686 us; speedup vs baseline: 3.9840x; 1.6881x over previous
//
#include <hip/hip_runtime.h>
#include <hip/hip_bf16.h>

// LearnableChebyshevKernelAttention, MI355X — MFMA, barrier-free main loop.
// Packed-f32 (v_pk_*) score math, register-lean repackaging: no explicit
// B-frag prefetch array (compiler hoists; explicit version spilled to
// scratch in R5: 172MB HBM traffic), one kk-group live at a time, pairs
// formed by even-aligned sub-register extraction. Per-component numerics
// BIT-IDENTICAL to the verified R3 kernel (absmax 1.95e-3).
// B=2, Q=M=1024, DIM=3, H=8, V=64, OUT=512, C=8.
//
// prep:      values [b,m,h,v] f32 -> Vt [b,h,v,m] bf16, out_w f32 -> bf16.
// cheb_attn: grid (32,8,2) = (qt, h, b), block 512 (8 waves), 2 blocks/CU.
//            Scores computed directly in the MFMA A-fragment register layout.
// proj:      flat bf16 [2048,512] @ Wb[n,k]^T via MFMA, frags from
//            L2-resident global. grid (32,16), block 256.

typedef __attribute__((ext_vector_type(8))) short short8v;
typedef __attribute__((ext_vector_type(4))) short short4v;
typedef __attribute__((ext_vector_type(4))) float f32x4;
typedef __attribute__((ext_vector_type(2))) float f32x2;

#define EPSF 1e-5f

__device__ __forceinline__ float frcp(float x) { return __builtin_amdgcn_rcpf(x); }
__device__ __forceinline__ short f2bf(float f) {
    __hip_bfloat16 h = __float2bfloat16(f);   // RNE
    return *reinterpret_cast<short*>(&h);
}

// ws layout (shorts): Vt bf16 [2*8*64*1024] | Wb bf16 [512*512] | flat bf16 [2*1024*512]
#define VT_ELEMS   (2u * 8u * 64u * 1024u)
#define WB_OFF_S   (VT_ELEMS)
#define FLAT_OFF_S (VT_ELEMS + 512u * 512u)

// ---------------------------------------------------------------- prep
// grid 288: blocks 0..255 transpose one (b,h,64m) values tile; 256..287 convert W.
__global__ __launch_bounds__(256) void prep(
    const float* __restrict__ vals, const float* __restrict__ outw,
    short* __restrict__ vt, short* __restrict__ wb)
{
    const int bid = blockIdx.x, t = threadIdx.x;
    if (bid < 256) {
        __shared__ float sf[64 * 68];
        const int b = bid >> 7, h = (bid >> 4) & 7, m0 = (bid & 15) * 64;
        #pragma unroll
        for (int fi = 0; fi < 4; ++fi) {
            const int idx = fi * 256 + t, mr = idx >> 4, c4 = idx & 15;
            const float4 v4 = *(const float4*)&vals[
                (((size_t)b * 1024 + m0 + mr) * 8 + h) * 64 + c4 * 4];
            *(float4*)&sf[mr * 68 + c4 * 4] = v4;
        }
        __syncthreads();
        const int v = t >> 2, mo = t & 3;
        short8v o0, o1;
        #pragma unroll
        for (int i = 0; i < 8; ++i) o0[i] = f2bf(sf[(mo * 16 + i) * 68 + v]);
        #pragma unroll
        for (int i = 0; i < 8; ++i) o1[i] = f2bf(sf[(mo * 16 + 8 + i) * 68 + v]);
        const size_t ob = ((size_t)(b * 8 + h) * 64 + v) * 1024 + m0 + mo * 16;
        *(short8v*)&vt[ob] = o0;
        *(short8v*)&vt[ob + 8] = o1;
    } else {
        const int wi = bid - 256;            // 0..31, 8192 floats each
        #pragma unroll
        for (int k = 0; k < 8; ++k) {
            const int fidx = wi * 8192 + k * 1024 + t * 4;
            const float4 f4 = *(const float4*)&outw[fidx];
            short4v s; s[0] = f2bf(f4.x); s[1] = f2bf(f4.y);
                       s[2] = f2bf(f4.z); s[3] = f2bf(f4.w);
            *(short4v*)&wb[fidx] = s;
        }
    }
}

// ---------------------------------------------------------------- cheb_attn
// grid (32, 8, 2) = (qt, h, b), block 512 (8 waves), 2 blocks/CU.
__global__ __launch_bounds__(512, 4) void cheb_attn(
    const float* __restrict__ qp, const float* __restrict__ kp,
    const unsigned char* __restrict__ msk,
    const float* __restrict__ ls, const float* __restrict__ cheb,
    const short* __restrict__ vt, short* __restrict__ flatb)
{
    __shared__ float s_kx[1024], s_ky[1024], s_kz[1024];   // kp SoA
    __shared__ __align__(8) unsigned char s_mask[1024];
    __shared__ float s_l1[4][32];
    __shared__ float s_pb[3][32 * 68];                      // groups 1..3 partial P

    const int t = threadIdx.x;
    const int qt = blockIdx.x, h = blockIdx.y, b = blockIdx.z;
    const int w = t >> 6, lane = t & 63;
    const int wg = w & 1, g = w >> 1;          // q band (16 rows), m group (256 m)
    const int arow = lane & 15, koct = lane >> 4;

    // stage kp (SoA) + mask
    #pragma unroll
    for (int mm_ = 0; mm_ < 2; ++mm_) {
        const int m = mm_ * 512 + t;
        const size_t base = ((size_t)b * 1024 + m) * 3;
        s_kx[m] = kp[base + 0];
        s_ky[m] = kp[base + 1];
        s_kz[m] = kp[base + 2];
    }
    *(unsigned short*)&s_mask[t * 2] =
        *(const unsigned short*)&msk[(size_t)b * 1024 + t * 2];

    // per-head constants (wave-uniform -> scalar regs). Verified numerics.
    const float lsv = ls[h];
    const float invls2 = 1.0f / (lsv * lsv);
    float cc[8]; float cs = 0.f;
    #pragma unroll
    for (int j = 0; j < 8; ++j) { cc[j] = cheb[h * 8 + j]; cs += cc[j]; }
    const float cm = cs * 0.125f;
    #pragma unroll
    for (int j = 0; j < 8; ++j) cc[j] -= cm;

    // this lane's q row (A-fragment row identity)
    const int qg = qt * 32 + wg * 16 + arow;
    const float qx = qp[((size_t)b * 1024 + qg) * 3 + 0];
    const float qy = qp[((size_t)b * 1024 + qg) * 3 + 1];
    const float qz = qp[((size_t)b * 1024 + qg) * 3 + 2];

    f32x4 acc[4] = {(f32x4)(0.f), (f32x4)(0.f), (f32x4)(0.f), (f32x4)(0.f)};
    const short* vtb = vt + ((size_t)(b * 8 + h) * 64) * 1024;
    f32x2 l1v = (f32x2)(0.f);     // even/odd partial L1 (folded once at end)

    __syncthreads();   // kp/mask staged — the ONLY pre-epilogue barrier

    #pragma unroll
    for (int tile = 0; tile < 4; ++tile) {
        const int m0 = g * 256 + tile * 64;
        short8v a[2];

        // ---- 16 scores as 8 float2 pairs (v_pk_* dual-pumped f32).
        //      One kk-group live at a time; per-component op sequence
        //      identical to the verified scalar code.
        #pragma unroll
        for (int kk = 0; kk < 2; ++kk) {
            const int mb = m0 + kk * 32 + koct * 8;
            const f32x4 kx0 = *(const f32x4*)&s_kx[mb];
            const f32x4 kx1 = *(const f32x4*)&s_kx[mb + 4];
            const f32x4 ky0 = *(const f32x4*)&s_ky[mb];
            const f32x4 ky1 = *(const f32x4*)&s_ky[mb + 4];
            const f32x4 kz0 = *(const f32x4*)&s_kz[mb];
            const f32x4 kz1 = *(const f32x4*)&s_kz[mb + 4];
            const uint2 mmv = *(const uint2*)&s_mask[mb];
            const bool anymask = (mmv.x | mmv.y) != 0u;
            #pragma unroll
            for (int p = 0; p < 4; ++p) {          // pair = scores j=2p, 2p+1
                const int e = (p & 1) * 2;          // even-aligned extraction
                f32x2 kxp, kyp, kzp;
                if (p < 2) { kxp[0] = kx0[e]; kxp[1] = kx0[e + 1];
                             kyp[0] = ky0[e]; kyp[1] = ky0[e + 1];
                             kzp[0] = kz0[e]; kzp[1] = kz0[e + 1]; }
                else       { kxp[0] = kx1[e]; kxp[1] = kx1[e + 1];
                             kyp[0] = ky1[e]; kyp[1] = ky1[e + 1];
                             kzp[0] = kz1[e]; kzp[1] = kz1[e + 1]; }
                const f32x2 dx = qx - kxp;
                const f32x2 dy = qy - kyp;
                const f32x2 dz = qz - kzp;
                const f32x2 x  = (dx * dx + dy * dy + dz * dz) * invls2;
                f32x2 rc; rc[0] = frcp(x[0] + 1.f); rc[1] = frcp(x[1] + 1.f);
                const f32x2 r  = (x - 1.f) * rc;
                const f32x2 r2 = r + r;
                f32x2 tp = (f32x2)(1.f), tc = r;
                f32x2 s  = cc[0] + cc[1] * r;
                #pragma unroll
                for (int c = 2; c < 8; ++c) {
                    const f32x2 tn = r2 * tc - tp;
                    s += cc[c] * tn; tp = tc; tc = tn;
                }
                if (anymask) {
                    const unsigned int mword = (p < 2) ? mmv.x : mmv.y;
                    if ((mword >> (((p * 2)     & 3) * 8)) & 0xffu) s[0] = 0.f;
                    if ((mword >> (((p * 2 + 1) & 3) * 8)) & 0xffu) s[1] = 0.f;
                }
                l1v += __builtin_elementwise_abs(s);
                a[kk][p * 2]     = f2bf(s[0]);
                a[kk][p * 2 + 1] = f2bf(s[1]);
            }
        }

        // ---- attend: B-frags inline from L2-resident Vt (compiler hoists)
        #pragma unroll
        for (int kk = 0; kk < 2; ++kk)
            #pragma unroll
            for (int f = 0; f < 4; ++f) {
                const short8v bf = *(const short8v*)
                    &vtb[(size_t)(f * 16 + arow) * 1024 + m0 + kk * 32 + koct * 8];
                acc[f] = __builtin_amdgcn_mfma_f32_16x16x32_bf16(
                    a[kk], bf, acc[f], 0, 0, 0);
            }
    }

    // L1 partial: lanes {arow, arow+16, arow+32, arow+48} share q row
    float l1p = l1v[0] + l1v[1];
    l1p += __shfl_xor(l1p, 16);
    l1p += __shfl_xor(l1p, 32);
    if (koct == 0) s_l1[g][wg * 16 + arow] = l1p;

    if (g > 0) {
        #pragma unroll
        for (int f = 0; f < 4; ++f)
            #pragma unroll
            for (int j = 0; j < 4; ++j)
                s_pb[g - 1][(wg * 16 + koct * 4 + j) * 68 + f * 16 + arow] = acc[f][j];
    }
    __syncthreads();
    if (g == 0) {
        float rden[4];
        #pragma unroll
        for (int j = 0; j < 4; ++j) {
            const int row = wg * 16 + koct * 4 + j;
            rden[j] = frcp(s_l1[0][row] + s_l1[1][row] + s_l1[2][row]
                         + s_l1[3][row] + EPSF);
        }
        #pragma unroll
        for (int f = 0; f < 4; ++f)
            #pragma unroll
            for (int j = 0; j < 4; ++j) {
                const int row = wg * 16 + koct * 4 + j;
                const int col = f * 16 + arow;
                const float v = (acc[f][j]
                    + s_pb[0][row * 68 + col]
                    + s_pb[1][row * 68 + col]
                    + s_pb[2][row * 68 + col]) * rden[j];
                flatb[((size_t)b * 1024 + qt * 32 + row) * 512 + h * 64 + col]
                    = f2bf(v);
            }
    }
}

// ---------------------------------------------------------------- proj
// out[2048,512] = flat[2048,512] @ Wb[n,k]^T, bf16 MFMA, frags direct from
// L2-resident global. grid (32,16): 64 rows x 32 n per block; block 256.
__global__ __launch_bounds__(256, 4) void proj(
    const short* __restrict__ flatb, const short* __restrict__ wb,
    float* __restrict__ out)
{
    const int t = threadIdx.x;
    const int r0 = blockIdx.x * 64, n0 = blockIdx.y * 32;
    const int w = t >> 6, lane = t & 63;
    const int arow = lane & 15, koct = lane >> 4;
    const int band = w * 16;

    f32x4 acc[2] = {(f32x4)(0.f), (f32x4)(0.f)};
    const short* ap = &flatb[(size_t)(r0 + band + arow) * 512];
    const short* b0 = &wb[(size_t)(n0 + arow) * 512];
    const short* b1 = &wb[(size_t)(n0 + 16 + arow) * 512];

    #pragma unroll 8
    for (int kk = 0; kk < 16; ++kk) {
        const int ko = kk * 32 + koct * 8;
        const short8v a   = *(const short8v*)&ap[ko];
        const short8v bf0 = *(const short8v*)&b0[ko];
        const short8v bf1 = *(const short8v*)&b1[ko];
        acc[0] = __builtin_amdgcn_mfma_f32_16x16x32_bf16(a, bf0, acc[0], 0, 0, 0);
        acc[1] = __builtin_amdgcn_mfma_f32_16x16x32_bf16(a, bf1, acc[1], 0, 0, 0);
    }
    #pragma unroll
    for (int f = 0; f < 2; ++f)
        #pragma unroll
        for (int j = 0; j < 4; ++j)
            out[((size_t)(r0 + band + koct * 4 + j)) * 512 + n0 + f * 16 + arow]
                = acc[f][j];
}

extern "C" void kernel_launch(void* const* d_in, const int* in_sizes, int n_in,
                              void* d_out, int out_size, void* d_ws, size_t ws_size,
                              hipStream_t stream) {
    const float* qp   = (const float*)d_in[0];
    const float* kp   = (const float*)d_in[1];
    const float* vals = (const float*)d_in[2];
    const unsigned char* msk = (const unsigned char*)d_in[3];
    const float* ls   = (const float*)d_in[4];
    const float* cheb = (const float*)d_in[5];
    const float* outw = (const float*)d_in[6];
    float* out = (float*)d_out;

    short* vtp   = (short*)d_ws;
    short* wbp   = vtp + WB_OFF_S;
    short* flatb = vtp + FLAT_OFF_S;

    prep<<<288, 256, 0, stream>>>(vals, outw, vtp, wbp);
    cheb_attn<<<dim3(32, 8, 2), 512, 0, stream>>>(qp, kp, msk, ls, cheb, vtp, flatb);
    proj<<<dim3(32, 16), 256, 0, stream>>>(flatb, wbp, out);
}